// Round 5
// baseline (171.251 us; speedup 1.0000x reference)
//
#include <hip/hip_runtime.h>
#include <hip/hip_bf16.h>
#include <float.h>

// Problem constants: S=8192 tokens, E=64 experts, C=256 capacity
constexpr int S = 8192;
constexpr int E = 64;
constexpr int C = 256;
constexpr int EC = E * C;            // 16384 floats per token region
constexpr int PRE_BLOCKS = 512;      // precompute blocks (4 waves x 4 tokens)
// ws layout: [0, S) float4 token records | then PRE_BLOCKS*128 floats partials
constexpr size_t WS_PARTIALS_OFF = (size_t)S * 4;   // in floats

// ---------------------------------------------------------------------------
// Kernel 1: per-token softmax + top-2 extraction. Writes a 16B record per
// token: (w1, w2, h1_bits, h2_bits) where h = e*C + c is the flat hot index
// in [0, 16384). Also emits per-block me/ce partial sums for l_aux.
// One wave per row (lane = expert); ballots extract the one-hot positions.
// ---------------------------------------------------------------------------
__global__ __launch_bounds__(256) void precompute_kernel(
        const float* __restrict__ logits,
        const float* __restrict__ mask1,
        const float* __restrict__ mask2,
        const float* __restrict__ loc1,
        const float* __restrict__ loc2,
        float4* __restrict__ recs,
        float* __restrict__ ws_partials) {
    __shared__ float me_s[4][64];
    __shared__ float ce_s[4][64];

    const int lane = threadIdx.x & 63;
    const int wave = threadIdx.x >> 6;

    float me_acc = 0.f, ce_acc = 0.f;

    #pragma unroll
    for (int r = 0; r < 4; ++r) {
        const int s = blockIdx.x * 16 + wave * 4 + r;

        // softmax over E=64 (one lane per expert)
        const float x = logits[(size_t)s * E + lane];
        float mx = x;
        #pragma unroll
        for (int off = 32; off > 0; off >>= 1) mx = fmaxf(mx, __shfl_xor(mx, off));
        const float ex = __expf(x - mx);
        float sum = ex;
        #pragma unroll
        for (int off = 32; off > 0; off >>= 1) sum += __shfl_xor(sum, off);
        const float g = ex / sum;

        const float m1v = mask1[(size_t)s * E + lane];
        const float m2v = mask2[(size_t)s * E + lane];
        me_acc += g;
        ce_acc += m1v;

        const int e1 = __ffsll(__ballot(m1v > 0.5f)) - 1;
        const int e2 = __ffsll(__ballot(m2v > 0.5f)) - 1;
        const float g1 = __shfl(g, e1);
        const float g2 = __shfl(g, e2);

        const float4 l1v = *reinterpret_cast<const float4*>(loc1 + (size_t)s * C + lane * 4);
        const float4 l2v = *reinterpret_cast<const float4*>(loc2 + (size_t)s * C + lane * 4);
        const int bm1 = (l1v.x > 0.5f ? 1 : 0) | (l1v.y > 0.5f ? 2 : 0) |
                        (l1v.z > 0.5f ? 4 : 0) | (l1v.w > 0.5f ? 8 : 0);
        const int bm2 = (l2v.x > 0.5f ? 1 : 0) | (l2v.y > 0.5f ? 2 : 0) |
                        (l2v.z > 0.5f ? 4 : 0) | (l2v.w > 0.5f ? 8 : 0);
        const int L1 = __ffsll(__ballot(bm1 != 0)) - 1;
        const int L2 = __ffsll(__ballot(bm2 != 0)) - 1;
        const int c1 = L1 * 4 + (__ffs(__shfl(bm1, L1)) - 1);
        const int c2 = L2 * 4 + (__ffs(__shfl(bm2, L2)) - 1);

        if (lane == 0) {
            const float denom = fmaxf(g1 + g2, FLT_EPSILON);
            float4 rec;
            rec.x = g1 / denom;
            rec.y = g2 / denom;
            rec.z = __int_as_float(e1 * C + c1);
            rec.w = __int_as_float(e2 * C + c2);
            recs[s] = rec;
        }
    }

    me_s[wave][lane] = me_acc;
    ce_s[wave][lane] = ce_acc;
    __syncthreads();
    if (threadIdx.x < 64) {
        const float me_b = me_s[0][lane] + me_s[1][lane] + me_s[2][lane] + me_s[3][lane];
        const float ce_b = ce_s[0][lane] + ce_s[1][lane] + ce_s[2][lane] + ce_s[3][lane];
        ws_partials[(size_t)blockIdx.x * 128 + lane]      = me_b;
        ws_partials[(size_t)blockIdx.x * 128 + 64 + lane] = ce_b;
    }
}

// ---------------------------------------------------------------------------
// Kernel 2: one block per token; pure streaming fill of the 64 KB region with
// the two hot values merged into the fill. Hot slot indices are block-uniform
// (SGPR via readfirstlane), so 15/16 unrolled iterations are a bare float4
// zero-store; only the matching k pays a vector compare+select. No barriers,
// no second pass, output written exactly once.
// Region = out + 1 + s*16384: 3 head scalars + 4095 aligned float4 + 1 tail.
// ---------------------------------------------------------------------------
__global__ __launch_bounds__(256) void fill_kernel(
        const float4* __restrict__ recs,
        float* __restrict__ out) {
    const int s   = blockIdx.x;
    const int tid = threadIdx.x;
    float* __restrict__ base = out + 1 + (size_t)s * EC;

    const float4 rec = recs[s];               // uniform 16B load (L2 broadcast)
    const float w1 = rec.x, w2 = rec.y;
    const int h1 = __float_as_int(rec.z);
    const int h2 = __float_as_int(rec.w);

    // head (floats 0..2) and tail (float 16383), rarely hot
    if (tid < 3)       base[tid]    = (h1 == tid)      ? w1 : ((h2 == tid)      ? w2 : 0.f);
    else if (tid == 3) base[EC - 1] = (h1 == EC - 1)   ? w1 : ((h2 == EC - 1)   ? w2 : 0.f);

    // vector region: float4 slot j covers floats [3+4j, 6+4j], j in [0,4095)
    const int j1 = (h1 >= 3 && h1 < EC - 1) ? ((h1 - 3) >> 2) : -1;
    const int j2 = (h2 >= 3 && h2 < EC - 1) ? ((h2 - 3) >> 2) : -1;
    const int r1 = (h1 - 3) & 3;
    const int r2 = (h2 - 3) & 3;
    const int k1 = __builtin_amdgcn_readfirstlane(j1 >= 0 ? (j1 >> 8) : 999);
    const int k2 = __builtin_amdgcn_readfirstlane(j2 >= 0 ? (j2 >> 8) : 999);
    const float4 hv1 = make_float4(r1 == 0 ? w1 : 0.f, r1 == 1 ? w1 : 0.f,
                                   r1 == 2 ? w1 : 0.f, r1 == 3 ? w1 : 0.f);
    const float4 hv2 = make_float4(r2 == 0 ? w2 : 0.f, r2 == 1 ? w2 : 0.f,
                                   r2 == 2 ? w2 : 0.f, r2 == 3 ? w2 : 0.f);
    const float4 z = make_float4(0.f, 0.f, 0.f, 0.f);

    #pragma unroll
    for (int k = 0; k < 16; ++k) {
        const int j = tid + (k << 8);
        float4 v = z;
        if (k == k1 && j == j1) v = hv1;   // scalar k-check; vector only on hit
        if (k == k2 && j == j2) v = hv2;
        if (j < 4095)
            *reinterpret_cast<float4*>(base + 3 + 4 * j) = v;
    }
}

// ---------------------------------------------------------------------------
// Kernel 3: l_aux = (E/S^2) * sum_e me_sum[e]*ce_sum[e] -> out[0].
// ---------------------------------------------------------------------------
__global__ __launch_bounds__(256) void laux_kernel(const float* __restrict__ ws_partials,
                                                   float* __restrict__ out) {
    __shared__ float mes[4][64];
    __shared__ float ces[4][64];
    const int e = threadIdx.x & 63;
    const int q = threadIdx.x >> 6;
    float me = 0.f, ce = 0.f;
    for (int b = q; b < PRE_BLOCKS; b += 4) {
        me += ws_partials[(size_t)b * 128 + e];
        ce += ws_partials[(size_t)b * 128 + 64 + e];
    }
    mes[q][e] = me;
    ces[q][e] = ce;
    __syncthreads();
    if (threadIdx.x < 64) {
        const float m = mes[0][e] + mes[1][e] + mes[2][e] + mes[3][e];
        const float c = ces[0][e] + ces[1][e] + ces[2][e] + ces[3][e];
        float prod = m * c;
        #pragma unroll
        for (int off = 32; off > 0; off >>= 1) prod += __shfl_xor(prod, off);
        if (e == 0) out[0] = prod * (float)E / ((float)S * (float)S);
    }
}

extern "C" void kernel_launch(void* const* d_in, const int* in_sizes, int n_in,
                              void* d_out, int out_size, void* d_ws, size_t ws_size,
                              hipStream_t stream) {
    const float* logits = (const float*)d_in[0];
    const float* mask1  = (const float*)d_in[1];
    const float* mask2  = (const float*)d_in[2];
    const float* loc1   = (const float*)d_in[3];
    const float* loc2   = (const float*)d_in[4];
    float* out = (float*)d_out;
    float* ws  = (float*)d_ws;

    float4* recs        = (float4*)ws;                      // S * 16 B
    float*  ws_partials = ws + WS_PARTIALS_OFF;             // PRE_BLOCKS * 128 floats

    // 1) tiny: per-token records + l_aux partials (22 MB read)
    precompute_kernel<<<PRE_BLOCKS, 256, 0, stream>>>(logits, mask1, mask2,
                                                      loc1, loc2, recs, ws_partials);

    // 2) single pass over the 537 MB output: pure fill with merged hot values
    fill_kernel<<<S, 256, 0, stream>>>(recs, out);

    // 3) l_aux reduce
    laux_kernel<<<1, 256, 0, stream>>>(ws_partials, out);
}

// Round 6
// 150.241 us; speedup vs baseline: 1.1398x; 1.1398x over previous
//
#include <hip/hip_runtime.h>
#include <hip/hip_bf16.h>
#include <float.h>

// Problem constants: S=8192 tokens, E=64 experts, C=256 capacity
constexpr int S = 8192;
constexpr int E = 64;
constexpr int C = 256;
constexpr int EC = E * C;                    // 16384 floats per token region
constexpr int PRE_BLOCKS = 512;              // precompute blocks (4 waves x 4 tokens)
constexpr unsigned N4 = 33554432u;           // aligned float4s covering floats [0, 134217728)
constexpr unsigned FILL_BLOCKS = N4 / 256u;  // 131072 — grid covers N4 exactly
// ws layout: [0, S) float4 token records | then PRE_BLOCKS*128 floats partials
constexpr size_t WS_PARTIALS_OFF = (size_t)S * 4;   // in floats

// ---------------------------------------------------------------------------
// Kernel 1: per-token softmax + top-2 extraction (R2 math, proven absmax=0).
// Writes a 16B record per token: (w1, w2, h1_bits, h2_bits), h = e*C + c.
// Also emits per-block me/ce partial sums for l_aux. NO writes to out.
// ---------------------------------------------------------------------------
__global__ __launch_bounds__(256) void precompute_kernel(
        const float* __restrict__ logits,
        const float* __restrict__ mask1,
        const float* __restrict__ mask2,
        const float* __restrict__ loc1,
        const float* __restrict__ loc2,
        float4* __restrict__ recs,
        float* __restrict__ ws_partials) {
    __shared__ float me_s[4][64];
    __shared__ float ce_s[4][64];

    const int lane = threadIdx.x & 63;
    const int wave = threadIdx.x >> 6;

    float me_acc = 0.f, ce_acc = 0.f;

    #pragma unroll
    for (int r = 0; r < 4; ++r) {
        const int s = blockIdx.x * 16 + wave * 4 + r;

        // softmax over E=64 (one lane per expert)
        const float x = logits[(size_t)s * E + lane];
        float mx = x;
        #pragma unroll
        for (int off = 32; off > 0; off >>= 1) mx = fmaxf(mx, __shfl_xor(mx, off));
        const float ex = __expf(x - mx);
        float sum = ex;
        #pragma unroll
        for (int off = 32; off > 0; off >>= 1) sum += __shfl_xor(sum, off);
        const float g = ex / sum;

        const float m1v = mask1[(size_t)s * E + lane];
        const float m2v = mask2[(size_t)s * E + lane];
        me_acc += g;
        ce_acc += m1v;

        const int e1 = __ffsll(__ballot(m1v > 0.5f)) - 1;
        const int e2 = __ffsll(__ballot(m2v > 0.5f)) - 1;
        const float g1 = __shfl(g, e1);
        const float g2 = __shfl(g, e2);

        const float4 l1v = *reinterpret_cast<const float4*>(loc1 + (size_t)s * C + lane * 4);
        const float4 l2v = *reinterpret_cast<const float4*>(loc2 + (size_t)s * C + lane * 4);
        const int bm1 = (l1v.x > 0.5f ? 1 : 0) | (l1v.y > 0.5f ? 2 : 0) |
                        (l1v.z > 0.5f ? 4 : 0) | (l1v.w > 0.5f ? 8 : 0);
        const int bm2 = (l2v.x > 0.5f ? 1 : 0) | (l2v.y > 0.5f ? 2 : 0) |
                        (l2v.z > 0.5f ? 4 : 0) | (l2v.w > 0.5f ? 8 : 0);
        const int L1 = __ffsll(__ballot(bm1 != 0)) - 1;
        const int L2 = __ffsll(__ballot(bm2 != 0)) - 1;
        const int c1 = L1 * 4 + (__ffs(__shfl(bm1, L1)) - 1);
        const int c2 = L2 * 4 + (__ffs(__shfl(bm2, L2)) - 1);

        if (lane == 0) {
            const float denom = fmaxf(g1 + g2, FLT_EPSILON);
            float4 rec;
            rec.x = g1 / denom;
            rec.y = g2 / denom;
            rec.z = __int_as_float(e1 * C + c1);
            rec.w = __int_as_float(e2 * C + c2);
            recs[s] = rec;
        }
    }

    me_s[wave][lane] = me_acc;
    ce_s[wave][lane] = ce_acc;
    __syncthreads();
    if (threadIdx.x < 64) {
        const float me_b = me_s[0][lane] + me_s[1][lane] + me_s[2][lane] + me_s[3][lane];
        const float ce_b = ce_s[0][lane] + ce_s[1][lane] + ce_s[2][lane] + ce_s[3][lane];
        ws_partials[(size_t)blockIdx.x * 128 + lane]      = me_b;
        ws_partials[(size_t)blockIdx.x * 128 + 64 + lane] = ce_b;
    }
}

// ---------------------------------------------------------------------------
// Kernel 2: pure fill, rocclr-fillBufferAligned shape. One aligned float4
// zero-store per thread, no guards, no branches (grid covers N4 exactly).
// Thread (0,0) additionally zeroes the final tail scalar. out[0] (l_aux slot)
// is zeroed here and overwritten by the finalize kernel afterwards.
// ---------------------------------------------------------------------------
__global__ __launch_bounds__(256) void fill_kernel(float4* __restrict__ out4,
                                                   float* __restrict__ out) {
    const unsigned j = blockIdx.x * 256u + threadIdx.x;
    out4[j] = make_float4(0.f, 0.f, 0.f, 0.f);
    if (j == 0) out[(size_t)S * EC] = 0.f;   // tail float index 134217728
}

// ---------------------------------------------------------------------------
// Kernel 3: finalize. Blocks 0..31: one thread per token scatters the two hot
// dwords (coalesced float4 rec loads). Block 32: l_aux reduce -> out[0].
// ---------------------------------------------------------------------------
__global__ __launch_bounds__(256) void finalize_kernel(
        const float4* __restrict__ recs,
        const float* __restrict__ ws_partials,
        float* __restrict__ out) {
    if (blockIdx.x < 32) {
        const int t = blockIdx.x * 256 + threadIdx.x;   // token id, [0, 8192)
        const float4 rec = recs[t];
        float* __restrict__ base = out + 1 + (size_t)t * EC;
        base[__float_as_int(rec.z)] = rec.x;
        base[__float_as_int(rec.w)] = rec.y;
    } else {
        __shared__ float mes[4][64];
        __shared__ float ces[4][64];
        const int e = threadIdx.x & 63;
        const int q = threadIdx.x >> 6;
        float me = 0.f, ce = 0.f;
        for (int b = q; b < PRE_BLOCKS; b += 4) {
            me += ws_partials[(size_t)b * 128 + e];
            ce += ws_partials[(size_t)b * 128 + 64 + e];
        }
        mes[q][e] = me;
        ces[q][e] = ce;
        __syncthreads();
        if (threadIdx.x < 64) {
            const float m = mes[0][e] + mes[1][e] + mes[2][e] + mes[3][e];
            const float c = ces[0][e] + ces[1][e] + ces[2][e] + ces[3][e];
            float prod = m * c;
            #pragma unroll
            for (int off = 32; off > 0; off >>= 1) prod += __shfl_xor(prod, off);
            if (e == 0) out[0] = prod * (float)E / ((float)S * (float)S);
        }
    }
}

extern "C" void kernel_launch(void* const* d_in, const int* in_sizes, int n_in,
                              void* d_out, int out_size, void* d_ws, size_t ws_size,
                              hipStream_t stream) {
    const float* logits = (const float*)d_in[0];
    const float* mask1  = (const float*)d_in[1];
    const float* mask2  = (const float*)d_in[2];
    const float* loc1   = (const float*)d_in[3];
    const float* loc2   = (const float*)d_in[4];
    float* out = (float*)d_out;
    float* ws  = (float*)d_ws;

    float4* recs        = (float4*)ws;              // S * 16 B
    float*  ws_partials = ws + WS_PARTIALS_OFF;     // PRE_BLOCKS * 128 floats

    // 1) tiny: per-token records + l_aux partials (22 MB read, no out writes)
    precompute_kernel<<<PRE_BLOCKS, 256, 0, stream>>>(logits, mask1, mask2,
                                                      loc1, loc2, recs, ws_partials);

    // 2) pure fill of the 537 MB output (rocclr fill shape: 1 float4/thread)
    fill_kernel<<<FILL_BLOCKS, 256, 0, stream>>>((float4*)out, out);

    // 3) scatter 16K hot dwords + l_aux -> out[0]
    finalize_kernel<<<33, 256, 0, stream>>>(recs, ws_partials, out);
}

// Round 8
// 142.163 us; speedup vs baseline: 1.2046x; 1.0568x over previous
//
#include <hip/hip_runtime.h>
#include <hip/hip_bf16.h>
#include <float.h>

// Problem constants: S=8192 tokens, E=64 experts, C=256 capacity
constexpr int S = 8192;
constexpr int E = 64;
constexpr int C = 256;
constexpr int EC = E * C;                 // 16384 floats per token region
constexpr int PRE_BLOCKS = 512;           // precompute blocks (4 waves x 4 tokens)
constexpr int FILL_BLOCKS = 8192;         // each fills 4096 float4 = 64 KB
// ws layout: [0, S) float4 token records | then PRE_BLOCKS*128 floats partials
constexpr size_t WS_PARTIALS_OFF = (size_t)S * 4;   // in floats

typedef float f32x4 __attribute__((ext_vector_type(4)));   // native vector for nontemporal stores

// ---------------------------------------------------------------------------
// Mega-kernel: blocks [0, 512) run precompute (softmax + top-2 -> 16B rec/token
// + me/ce partials); blocks [512, 8704) stream-fill the 537 MB output with
// pure nontemporal float4 zero-stores (16/thread, contiguous 64 KB per block,
// no guards). Precompute is dispatched first so its latency-bound work hides
// under the write-bound fill. No cross-path ordering needed: precompute
// writes only ws, fill writes only out.
// ---------------------------------------------------------------------------
__global__ __launch_bounds__(256) void mega_kernel(
        const float* __restrict__ logits,
        const float* __restrict__ mask1,
        const float* __restrict__ mask2,
        const float* __restrict__ loc1,
        const float* __restrict__ loc2,
        float4* __restrict__ recs,
        float* __restrict__ ws_partials,
        float* __restrict__ out) {
    __shared__ float me_s[4][64];
    __shared__ float ce_s[4][64];

    if (blockIdx.x >= PRE_BLOCKS) {
        // ---- fill path: one contiguous 64 KB chunk, 16 f32x4 stores/thread ----
        const unsigned blk = blockIdx.x - PRE_BLOCKS;
        f32x4* __restrict__ p = reinterpret_cast<f32x4*>(out) +
                                (size_t)blk * 4096 + threadIdx.x;
        const f32x4 z = {0.f, 0.f, 0.f, 0.f};
        #pragma unroll
        for (int k = 0; k < 16; ++k)
            __builtin_nontemporal_store(z, p + (k << 8));
        if (blk == 0 && threadIdx.x == 0)
            out[(size_t)S * EC] = 0.f;       // tail scalar, float index 134217728
        return;
    }

    // ---- precompute path (R2 math, proven absmax=0) ----
    const int lane = threadIdx.x & 63;
    const int wave = threadIdx.x >> 6;

    float me_acc = 0.f, ce_acc = 0.f;

    #pragma unroll
    for (int r = 0; r < 4; ++r) {
        const int s = blockIdx.x * 16 + wave * 4 + r;

        // softmax over E=64 (one lane per expert)
        const float x = logits[(size_t)s * E + lane];
        float mx = x;
        #pragma unroll
        for (int off = 32; off > 0; off >>= 1) mx = fmaxf(mx, __shfl_xor(mx, off));
        const float ex = __expf(x - mx);
        float sum = ex;
        #pragma unroll
        for (int off = 32; off > 0; off >>= 1) sum += __shfl_xor(sum, off);
        const float g = ex / sum;

        const float m1v = mask1[(size_t)s * E + lane];
        const float m2v = mask2[(size_t)s * E + lane];
        me_acc += g;
        ce_acc += m1v;

        const int e1 = __ffsll(__ballot(m1v > 0.5f)) - 1;
        const int e2 = __ffsll(__ballot(m2v > 0.5f)) - 1;
        const float g1 = __shfl(g, e1);
        const float g2 = __shfl(g, e2);

        const float4 l1v = *reinterpret_cast<const float4*>(loc1 + (size_t)s * C + lane * 4);
        const float4 l2v = *reinterpret_cast<const float4*>(loc2 + (size_t)s * C + lane * 4);
        const int bm1 = (l1v.x > 0.5f ? 1 : 0) | (l1v.y > 0.5f ? 2 : 0) |
                        (l1v.z > 0.5f ? 4 : 0) | (l1v.w > 0.5f ? 8 : 0);
        const int bm2 = (l2v.x > 0.5f ? 1 : 0) | (l2v.y > 0.5f ? 2 : 0) |
                        (l2v.z > 0.5f ? 4 : 0) | (l2v.w > 0.5f ? 8 : 0);
        const int L1 = __ffsll(__ballot(bm1 != 0)) - 1;
        const int L2 = __ffsll(__ballot(bm2 != 0)) - 1;
        const int c1 = L1 * 4 + (__ffs(__shfl(bm1, L1)) - 1);
        const int c2 = L2 * 4 + (__ffs(__shfl(bm2, L2)) - 1);

        if (lane == 0) {
            const float denom = fmaxf(g1 + g2, FLT_EPSILON);
            float4 rec;
            rec.x = g1 / denom;
            rec.y = g2 / denom;
            rec.z = __int_as_float(e1 * C + c1);
            rec.w = __int_as_float(e2 * C + c2);
            recs[s] = rec;
        }
    }

    me_s[wave][lane] = me_acc;
    ce_s[wave][lane] = ce_acc;
    __syncthreads();
    if (threadIdx.x < 64) {
        const float me_b = me_s[0][lane] + me_s[1][lane] + me_s[2][lane] + me_s[3][lane];
        const float ce_b = ce_s[0][lane] + ce_s[1][lane] + ce_s[2][lane] + ce_s[3][lane];
        ws_partials[(size_t)blockIdx.x * 128 + lane]      = me_b;
        ws_partials[(size_t)blockIdx.x * 128 + 64 + lane] = ce_b;
    }
}

// ---------------------------------------------------------------------------
// Finalize: blocks 0..31: one thread per token scatters the two hot dwords
// (coalesced float4 rec loads). Block 32: l_aux reduce -> out[0].
// ---------------------------------------------------------------------------
__global__ __launch_bounds__(256) void finalize_kernel(
        const float4* __restrict__ recs,
        const float* __restrict__ ws_partials,
        float* __restrict__ out) {
    if (blockIdx.x < 32) {
        const int t = blockIdx.x * 256 + threadIdx.x;   // token id, [0, 8192)
        const float4 rec = recs[t];
        float* __restrict__ base = out + 1 + (size_t)t * EC;
        base[__float_as_int(rec.z)] = rec.x;
        base[__float_as_int(rec.w)] = rec.y;
    } else {
        __shared__ float mes[4][64];
        __shared__ float ces[4][64];
        const int e = threadIdx.x & 63;
        const int q = threadIdx.x >> 6;
        float me = 0.f, ce = 0.f;
        for (int b = q; b < PRE_BLOCKS; b += 4) {
            me += ws_partials[(size_t)b * 128 + e];
            ce += ws_partials[(size_t)b * 128 + 64 + e];
        }
        mes[q][e] = me;
        ces[q][e] = ce;
        __syncthreads();
        if (threadIdx.x < 64) {
            const float m = mes[0][e] + mes[1][e] + mes[2][e] + mes[3][e];
            const float c = ces[0][e] + ces[1][e] + ces[2][e] + ces[3][e];
            float prod = m * c;
            #pragma unroll
            for (int off = 32; off > 0; off >>= 1) prod += __shfl_xor(prod, off);
            if (e == 0) out[0] = prod * (float)E / ((float)S * (float)S);
        }
    }
}

extern "C" void kernel_launch(void* const* d_in, const int* in_sizes, int n_in,
                              void* d_out, int out_size, void* d_ws, size_t ws_size,
                              hipStream_t stream) {
    const float* logits = (const float*)d_in[0];
    const float* mask1  = (const float*)d_in[1];
    const float* mask2  = (const float*)d_in[2];
    const float* loc1   = (const float*)d_in[3];
    const float* loc2   = (const float*)d_in[4];
    float* out = (float*)d_out;
    float* ws  = (float*)d_ws;

    float4* recs        = (float4*)ws;              // S * 16 B
    float*  ws_partials = ws + WS_PARTIALS_OFF;     // PRE_BLOCKS * 128 floats

    // 1) fused: precompute (512 blocks, dispatched first) + 537 MB pure fill
    mega_kernel<<<PRE_BLOCKS + FILL_BLOCKS, 256, 0, stream>>>(
        logits, mask1, mask2, loc1, loc2, recs, ws_partials, out);

    // 2) scatter 16K hot dwords + l_aux -> out[0]
    finalize_kernel<<<33, 256, 0, stream>>>(recs, ws_partials, out);
}